// Round 1
// baseline (1079.316 us; speedup 1.0000x reference)
//
#include <hip/hip_runtime.h>

// LightGCN propagation: 3 × (weighted SpMM scatter-add) + hop-mean.
// Node matrix 500000x64 f32 (128 MB) fits in the 256 MB L3.

#define USER_NUM  300000
#define ITEM_NUM  200000
#define N_NODES   500000
#define EMBED_DIM 64
#define N_EDGES   1250000
#define NV   (N_NODES * EMBED_DIM)   // 32,000,000 floats
#define NV4  (NV / 4)                // 8,000,000 float4

__global__ void init_kernel(const float4* __restrict__ ue,
                            const float4* __restrict__ ie,
                            float4* __restrict__ h,
                            float4* __restrict__ hn,
                            float4* __restrict__ acc) {
    int i = blockIdx.x * blockDim.x + threadIdx.x;
    if (i >= NV4) return;
    const int ub = USER_NUM * EMBED_DIM / 4;   // 4,800,000 (boundary is float4-aligned)
    float4 v = (i < ub) ? ue[i] : ie[i - ub];
    h[i]   = v;
    acc[i] = v;
    hn[i]  = make_float4(0.f, 0.f, 0.f, 0.f);
}

// One 64-lane wave per edge: lane d handles dim d. Gather read and atomic
// scatter are both 256 B contiguous per wave (coalesced).
__global__ void spmm_kernel(const float* __restrict__ h,
                            float*       __restrict__ hn,
                            const int*   __restrict__ src,
                            const int*   __restrict__ dst,
                            const float* __restrict__ w) {
    int gid   = blockIdx.x * blockDim.x + threadIdx.x;
    int wave  = gid >> 6;
    int lane  = gid & 63;
    int nwave = (gridDim.x * blockDim.x) >> 6;
    for (int e = wave; e < N_EDGES; e += nwave) {
        int   s  = src[e];
        int   d  = dst[e];
        float ww = w[e];
        float v  = h[s * 64 + lane] * ww;      // max index 31,999,999 < 2^31
        atomicAdd(&hn[d * 64 + lane], v);
    }
}

// acc += hn; zero the ping-pong partner buffer (it becomes next layer's hn).
// Last layer fuses the mean (x0.25) and skips zeroing.
template <int LAST>
__global__ void accum_kernel(float4* __restrict__ acc,
                             const float4* __restrict__ hn,
                             float4* __restrict__ zbuf) {
    int i = blockIdx.x * blockDim.x + threadIdx.x;
    if (i >= NV4) return;
    float4 a = acc[i];
    float4 n = hn[i];
    a.x += n.x; a.y += n.y; a.z += n.z; a.w += n.w;
    if (LAST) { a.x *= 0.25f; a.y *= 0.25f; a.z *= 0.25f; a.w *= 0.25f; }
    acc[i] = a;
    if (!LAST) zbuf[i] = make_float4(0.f, 0.f, 0.f, 0.f);
}

extern "C" void kernel_launch(void* const* d_in, const int* in_sizes, int n_in,
                              void* d_out, int out_size, void* d_ws, size_t ws_size,
                              hipStream_t stream) {
    const float* ue  = (const float*)d_in[0];
    const float* ie  = (const float*)d_in[1];
    const float* w   = (const float*)d_in[2];
    const int*   src = (const int*)d_in[3];
    const int*   dst = (const int*)d_in[4];

    float* acc = (float*)d_out;          // 128 MB output doubles as accumulator
    float* A   = (float*)d_ws;           // h / hn ping-pong, 128 MB each
    float* B   = A + NV;

    const int TB = 256;
    const int egrid = (NV4 + TB - 1) / TB;   // 31250 blocks for elementwise
    const int sgrid = 4096;                  // grid-stride: 16384 waves over 1.25M edges

    // h = A = concat(ue, ie); acc = same; B = 0
    init_kernel<<<egrid, TB, 0, stream>>>((const float4*)ue, (const float4*)ie,
                                          (float4*)A, (float4*)B, (float4*)acc);

    // layer 0: A -> B; acc += B; zero A
    spmm_kernel<<<sgrid, TB, 0, stream>>>(A, B, src, dst, w);
    accum_kernel<0><<<egrid, TB, 0, stream>>>((float4*)acc, (const float4*)B, (float4*)A);

    // layer 1: B -> A; acc += A; zero B
    spmm_kernel<<<sgrid, TB, 0, stream>>>(B, A, src, dst, w);
    accum_kernel<0><<<egrid, TB, 0, stream>>>((float4*)acc, (const float4*)A, (float4*)B);

    // layer 2: A -> B; acc = (acc + B) * 0.25
    spmm_kernel<<<sgrid, TB, 0, stream>>>(A, B, src, dst, w);
    accum_kernel<1><<<egrid, TB, 0, stream>>>((float4*)acc, (const float4*)B, nullptr);
}

// Round 2
// 925.247 us; speedup vs baseline: 1.1665x; 1.1665x over previous
//
#include <hip/hip_runtime.h>

// LightGCN propagation: CSR-by-dst (built on device each call) + gather SpMM
// fused with hop accumulation. No f32 atomics in the hot loops.

#define USER_NUM  300000
#define ITEM_NUM  200000
#define N_NODES   500000
#define EMBED_DIM 64
#define N_EDGES   1250000
#define NV   (N_NODES * EMBED_DIM)   // 32,000,000 floats
#define NV4  (NV / 4)                // 8,000,000 float4
#define CHUNK   2048                 // elements per scan block (256 thr x 8)
#define NCHUNK  ((N_NODES + CHUNK - 1) / CHUNK)   // 245

// ---------------- init: h = acc = concat(ue, ie) ----------------
__global__ void init_kernel(const float4* __restrict__ ue,
                            const float4* __restrict__ ie,
                            float4* __restrict__ h,
                            float4* __restrict__ acc) {
    int i = blockIdx.x * blockDim.x + threadIdx.x;
    if (i >= NV4) return;
    const int ub = USER_NUM * EMBED_DIM / 4;   // 4,800,000
    float4 v = (i < ub) ? ue[i] : ie[i - ub];
    h[i]   = v;
    acc[i] = v;
}

// ---------------- CSR build ----------------
__global__ void hist_kernel(const int* __restrict__ dst, int* __restrict__ deg) {
    int e = blockIdx.x * blockDim.x + threadIdx.x;
    if (e < N_EDGES) atomicAdd(&deg[dst[e]], 1);
}

// per-chunk exclusive scan; chunk totals -> csum
__global__ void scan1_kernel(const int* __restrict__ deg,
                             int* __restrict__ offs,
                             int* __restrict__ csum) {
    __shared__ int lds[256];
    int b = blockIdx.x, t = threadIdx.x;
    int base = b * CHUNK + t * 8;
    int v[8], sum = 0;
    #pragma unroll
    for (int i = 0; i < 8; ++i) {
        int idx = base + i;
        v[i] = (idx < N_NODES) ? deg[idx] : 0;
        sum += v[i];
    }
    lds[t] = sum;
    __syncthreads();
    for (int off = 1; off < 256; off <<= 1) {
        int x = (t >= off) ? lds[t - off] : 0;
        __syncthreads();
        if (t >= off) lds[t] += x;
        __syncthreads();
    }
    int excl = lds[t] - sum;
    if (t == 255) csum[b] = lds[255];
    int run = excl;
    #pragma unroll
    for (int i = 0; i < 8; ++i) {
        int idx = base + i;
        if (idx < N_NODES) offs[idx] = run;
        run += v[i];
    }
}

// exclusive scan of the (<=256) chunk sums, single block
__global__ void scan2_kernel(int* __restrict__ csum) {
    __shared__ int lds[256];
    int t = threadIdx.x;
    int v = (t < NCHUNK) ? csum[t] : 0;
    lds[t] = v;
    __syncthreads();
    for (int off = 1; off < 256; off <<= 1) {
        int x = (t >= off) ? lds[t - off] : 0;
        __syncthreads();
        if (t >= off) lds[t] += x;
        __syncthreads();
    }
    if (t < NCHUNK) csum[t] = lds[t] - v;   // exclusive
}

__global__ void scan3_kernel(int* __restrict__ offs, const int* __restrict__ csum) {
    int i = blockIdx.x * blockDim.x + threadIdx.x;
    if (i < N_NODES) offs[i] += csum[i / CHUNK];
    if (i == 0) offs[N_NODES] = N_EDGES;
}

__global__ void scatter_kernel(const int* __restrict__ src,
                               const int* __restrict__ dst,
                               const float* __restrict__ w,
                               const int* __restrict__ offs,
                               int* __restrict__ cur,
                               int* __restrict__ ssrc,
                               float* __restrict__ sw) {
    int e = blockIdx.x * blockDim.x + threadIdx.x;
    if (e >= N_EDGES) return;
    int d = dst[e];
    int p = offs[d] + atomicAdd(&cur[d], 1);
    ssrc[p] = src[e];
    sw[p]   = w[e];
}

// ---------------- fused gather-SpMM + accumulate ----------------
// one wave per dst node, lane = dim
template <int LAST>
__global__ void fused_kernel(const float* __restrict__ h,
                             float*       __restrict__ hn,
                             float*       __restrict__ acc,
                             const int*   __restrict__ offs,
                             const int*   __restrict__ ssrc,
                             const float* __restrict__ sw) {
    int gid  = blockIdx.x * blockDim.x + threadIdx.x;
    int n    = gid >> 6;
    int lane = gid & 63;
    if (n >= N_NODES) return;
    int beg = offs[n], end = offs[n + 1];
    float s0 = 0.f, s1 = 0.f;
    int e = beg;
    for (; e + 2 <= end; e += 2) {
        int   i0 = ssrc[e],   i1 = ssrc[e + 1];
        float w0 = sw[e],     w1 = sw[e + 1];
        s0 += w0 * h[i0 * 64 + lane];
        s1 += w1 * h[i1 * 64 + lane];
    }
    if (e < end) s0 += sw[e] * h[ssrc[e] * 64 + lane];
    float s = s0 + s1;
    int o = n * 64 + lane;
    if (!LAST) hn[o] = s;
    float a = acc[o] + s;
    if (LAST) a *= 0.25f;
    acc[o] = a;
}

// ---------------- fallback (atomic) path kernels ----------------
__global__ void init_fb_kernel(const float4* __restrict__ ue,
                               const float4* __restrict__ ie,
                               float4* __restrict__ h,
                               float4* __restrict__ hn,
                               float4* __restrict__ acc) {
    int i = blockIdx.x * blockDim.x + threadIdx.x;
    if (i >= NV4) return;
    const int ub = USER_NUM * EMBED_DIM / 4;
    float4 v = (i < ub) ? ue[i] : ie[i - ub];
    h[i] = v; acc[i] = v;
    hn[i] = make_float4(0.f, 0.f, 0.f, 0.f);
}

__global__ void spmm_fb_kernel(const float* __restrict__ h, float* __restrict__ hn,
                               const int* __restrict__ src, const int* __restrict__ dst,
                               const float* __restrict__ w) {
    int gid = blockIdx.x * blockDim.x + threadIdx.x;
    int wave = gid >> 6, lane = gid & 63;
    int nwave = (gridDim.x * blockDim.x) >> 6;
    for (int e = wave; e < N_EDGES; e += nwave) {
        float v = h[src[e] * 64 + lane] * w[e];
        atomicAdd(&hn[dst[e] * 64 + lane], v);
    }
}

template <int LAST>
__global__ void accum_fb_kernel(float4* __restrict__ acc, const float4* __restrict__ hn,
                                float4* __restrict__ zbuf) {
    int i = blockIdx.x * blockDim.x + threadIdx.x;
    if (i >= NV4) return;
    float4 a = acc[i], n = hn[i];
    a.x += n.x; a.y += n.y; a.z += n.z; a.w += n.w;
    if (LAST) { a.x *= 0.25f; a.y *= 0.25f; a.z *= 0.25f; a.w *= 0.25f; }
    acc[i] = a;
    if (!LAST) zbuf[i] = make_float4(0.f, 0.f, 0.f, 0.f);
}

extern "C" void kernel_launch(void* const* d_in, const int* in_sizes, int n_in,
                              void* d_out, int out_size, void* d_ws, size_t ws_size,
                              hipStream_t stream) {
    const float* ue  = (const float*)d_in[0];
    const float* ie  = (const float*)d_in[1];
    const float* w   = (const float*)d_in[2];
    const int*   src = (const int*)d_in[3];
    const int*   dst = (const int*)d_in[4];

    float* acc = (float*)d_out;

    // workspace layout
    float* A    = (float*)d_ws;
    float* B    = A + NV;
    int*   offs = (int*)(B + NV);             // N_NODES+1
    int*   cur  = offs + (N_NODES + 1);       // N_NODES (doubles as deg)
    int*   csum = cur + N_NODES;              // 256
    int*   ssrc = csum + 256;                 // N_EDGES
    float* sw   = (float*)(ssrc + N_EDGES);   // N_EDGES

    const size_t needed = (size_t)2 * NV * 4
                        + (size_t)(N_NODES + 1 + N_NODES + 256 + N_EDGES) * 4
                        + (size_t)N_EDGES * 4;

    const int TB = 256;
    const int egrid = NV4 / TB;                       // 31250
    const int ngrid = (N_EDGES + TB - 1) / TB;        // 4883
    const int fgrid = (N_NODES * 64) / TB;            // 125000

    if (ws_size >= needed) {
        // ---- CSR build (deg/cursors in `cur`) ----
        hipMemsetAsync(cur, 0, (size_t)N_NODES * 4, stream);
        hist_kernel<<<ngrid, TB, 0, stream>>>(dst, cur);
        scan1_kernel<<<NCHUNK, 256, 0, stream>>>(cur, offs, csum);
        scan2_kernel<<<1, 256, 0, stream>>>(csum);
        scan3_kernel<<<(N_NODES + TB - 1) / TB, TB, 0, stream>>>(offs, csum);
        hipMemsetAsync(cur, 0, (size_t)N_NODES * 4, stream);
        scatter_kernel<<<ngrid, TB, 0, stream>>>(src, dst, w, offs, cur, ssrc, sw);

        // ---- propagation ----
        init_kernel<<<egrid, TB, 0, stream>>>((const float4*)ue, (const float4*)ie,
                                              (float4*)A, (float4*)acc);
        fused_kernel<0><<<fgrid, TB, 0, stream>>>(A, B, acc, offs, ssrc, sw);
        fused_kernel<0><<<fgrid, TB, 0, stream>>>(B, A, acc, offs, ssrc, sw);
        fused_kernel<1><<<fgrid, TB, 0, stream>>>(A, nullptr, acc, offs, ssrc, sw);
    } else {
        // ---- fallback: round-1 atomic path ----
        const int sgrid = 4096;
        init_fb_kernel<<<egrid, TB, 0, stream>>>((const float4*)ue, (const float4*)ie,
                                                 (float4*)A, (float4*)B, (float4*)acc);
        spmm_fb_kernel<<<sgrid, TB, 0, stream>>>(A, B, src, dst, w);
        accum_fb_kernel<0><<<egrid, TB, 0, stream>>>((float4*)acc, (const float4*)B, (float4*)A);
        spmm_fb_kernel<<<sgrid, TB, 0, stream>>>(B, A, src, dst, w);
        accum_fb_kernel<0><<<egrid, TB, 0, stream>>>((float4*)acc, (const float4*)A, (float4*)B);
        spmm_fb_kernel<<<sgrid, TB, 0, stream>>>(A, B, src, dst, w);
        accum_fb_kernel<1><<<egrid, TB, 0, stream>>>((float4*)acc, (const float4*)B, nullptr);
    }
}

// Round 3
// 685.169 us; speedup vs baseline: 1.5753x; 1.3504x over previous
//
#include <hip/hip_runtime.h>

// LightGCN: out = 0.25*(h0 + h1 + h2 + h3), h_{k+1} = A_w · h_k.
// CSR-by-dst built on device; pure gather SpMM (no f32 atomics, no acc RMW).
// h0 is never materialized: layer-1 and the final kernel read ue/ie directly.

#define USER_NUM  300000
#define ITEM_NUM  200000
#define N_NODES   500000
#define EMBED_DIM 64
#define N_EDGES   1250000
#define NV   (N_NODES * EMBED_DIM)   // 32,000,000 floats
#define NV4  (NV / 4)
#define CHUNK   2048
#define NCHUNK  ((N_NODES + CHUNK - 1) / CHUNK)   // 245

// ---------------- CSR build ----------------
__global__ void hist_kernel(const int* __restrict__ dst, int* __restrict__ deg) {
    int e = blockIdx.x * blockDim.x + threadIdx.x;
    if (e < N_EDGES) atomicAdd(&deg[dst[e]], 1);
}

__global__ void scan1_kernel(const int* __restrict__ deg,
                             int* __restrict__ offs,
                             int* __restrict__ csum) {
    __shared__ int lds[256];
    int b = blockIdx.x, t = threadIdx.x;
    int base = b * CHUNK + t * 8;
    int v[8], sum = 0;
    #pragma unroll
    for (int i = 0; i < 8; ++i) {
        int idx = base + i;
        v[i] = (idx < N_NODES) ? deg[idx] : 0;
        sum += v[i];
    }
    lds[t] = sum;
    __syncthreads();
    for (int off = 1; off < 256; off <<= 1) {
        int x = (t >= off) ? lds[t - off] : 0;
        __syncthreads();
        if (t >= off) lds[t] += x;
        __syncthreads();
    }
    int excl = lds[t] - sum;
    if (t == 255) csum[b] = lds[255];
    int run = excl;
    #pragma unroll
    for (int i = 0; i < 8; ++i) {
        int idx = base + i;
        if (idx < N_NODES) offs[idx] = run;
        run += v[i];
    }
}

__global__ void scan2_kernel(int* __restrict__ csum) {
    __shared__ int lds[256];
    int t = threadIdx.x;
    int v = (t < NCHUNK) ? csum[t] : 0;
    lds[t] = v;
    __syncthreads();
    for (int off = 1; off < 256; off <<= 1) {
        int x = (t >= off) ? lds[t - off] : 0;
        __syncthreads();
        if (t >= off) lds[t] += x;
        __syncthreads();
    }
    if (t < NCHUNK) csum[t] = lds[t] - v;
}

__global__ void scan3_kernel(int* __restrict__ offs, const int* __restrict__ csum) {
    int i = blockIdx.x * blockDim.x + threadIdx.x;
    if (i < N_NODES) offs[i] += csum[i / CHUNK];
    if (i == 0) offs[N_NODES] = N_EDGES;
}

// pack sorted edge as int2{src, float_bits(w)} -> one 8B load per edge later
__global__ void scatter_kernel(const int* __restrict__ src,
                               const int* __restrict__ dst,
                               const float* __restrict__ w,
                               const int* __restrict__ offs,
                               int* __restrict__ cur,
                               int2* __restrict__ pe) {
    int e = blockIdx.x * blockDim.x + threadIdx.x;
    if (e >= N_EDGES) return;
    int d = dst[e];
    int p = offs[d] + atomicAdd(&cur[d], 1);
    pe[p] = make_int2(src[e], __float_as_int(w[e]));
}

// ---------------- gather SpMM ----------------
__device__ __forceinline__ float gsrc(const float* __restrict__ hsrc,
                                      const float* __restrict__ ue,
                                      const float* __restrict__ ie,
                                      int s, int lane, bool fromEmb) {
    if (!fromEmb) return hsrc[(size_t)s * 64 + lane];
    // wave-uniform branch (all 64 lanes share the same edge/src node)
    return (s < USER_NUM) ? ue[(size_t)s * 64 + lane]
                          : ie[(size_t)(s - USER_NUM) * 64 + lane];
}

// one wave per dst node, lane = dim; hout[n] written exactly once
template <int FROM_EMB>
__global__ void layer_kernel(const float* __restrict__ hsrc,
                             const float* __restrict__ ue,
                             const float* __restrict__ ie,
                             float* __restrict__ hout,
                             const int* __restrict__ offs,
                             const int2* __restrict__ pe) {
    int gid  = blockIdx.x * blockDim.x + threadIdx.x;
    int n    = gid >> 6;
    int lane = gid & 63;
    if (n >= N_NODES) return;
    int beg = offs[n], end = offs[n + 1];
    float s0 = 0.f, s1 = 0.f;
    int e = beg;
    for (; e + 2 <= end; e += 2) {
        int2 p0 = pe[e], p1 = pe[e + 1];
        s0 += __int_as_float(p0.y) * gsrc(hsrc, ue, ie, p0.x, lane, FROM_EMB);
        s1 += __int_as_float(p1.y) * gsrc(hsrc, ue, ie, p1.x, lane, FROM_EMB);
    }
    if (e < end) {
        int2 p0 = pe[e];
        s0 += __int_as_float(p0.y) * gsrc(hsrc, ue, ie, p0.x, lane, FROM_EMB);
    }
    hout[(size_t)n * 64 + lane] = s0 + s1;
}

// gather h3 from h2, then out = 0.25*(h0 + h1 + h2 + h3); h0 from ue/ie
__global__ void final_kernel(const float* __restrict__ ue,
                             const float* __restrict__ ie,
                             const float* __restrict__ h1,
                             const float* __restrict__ h2,
                             float* __restrict__ out,
                             const int* __restrict__ offs,
                             const int2* __restrict__ pe) {
    int gid  = blockIdx.x * blockDim.x + threadIdx.x;
    int n    = gid >> 6;
    int lane = gid & 63;
    if (n >= N_NODES) return;
    int beg = offs[n], end = offs[n + 1];
    float s0 = 0.f, s1 = 0.f;
    int e = beg;
    for (; e + 2 <= end; e += 2) {
        int2 p0 = pe[e], p1 = pe[e + 1];
        s0 += __int_as_float(p0.y) * h2[(size_t)p0.x * 64 + lane];
        s1 += __int_as_float(p1.y) * h2[(size_t)p1.x * 64 + lane];
    }
    if (e < end) {
        int2 p0 = pe[e];
        s0 += __int_as_float(p0.y) * h2[(size_t)p0.x * 64 + lane];
    }
    size_t o = (size_t)n * 64 + lane;
    float h0v = (n < USER_NUM) ? ue[o] : ie[o - (size_t)USER_NUM * 64];
    out[o] = 0.25f * (h0v + h1[o] + h2[o] + (s0 + s1));
}

// ---------------- fallback (round-1 atomic) path ----------------
__global__ void init_fb_kernel(const float4* __restrict__ ue,
                               const float4* __restrict__ ie,
                               float4* __restrict__ h,
                               float4* __restrict__ hn,
                               float4* __restrict__ acc) {
    int i = blockIdx.x * blockDim.x + threadIdx.x;
    if (i >= NV4) return;
    const int ub = USER_NUM * EMBED_DIM / 4;
    float4 v = (i < ub) ? ue[i] : ie[i - ub];
    h[i] = v; acc[i] = v;
    hn[i] = make_float4(0.f, 0.f, 0.f, 0.f);
}

__global__ void spmm_fb_kernel(const float* __restrict__ h, float* __restrict__ hn,
                               const int* __restrict__ src, const int* __restrict__ dst,
                               const float* __restrict__ w) {
    int gid = blockIdx.x * blockDim.x + threadIdx.x;
    int wave = gid >> 6, lane = gid & 63;
    int nwave = (gridDim.x * blockDim.x) >> 6;
    for (int e = wave; e < N_EDGES; e += nwave) {
        float v = h[src[e] * 64 + lane] * w[e];
        atomicAdd(&hn[dst[e] * 64 + lane], v);
    }
}

template <int LAST>
__global__ void accum_fb_kernel(float4* __restrict__ acc, const float4* __restrict__ hn,
                                float4* __restrict__ zbuf) {
    int i = blockIdx.x * blockDim.x + threadIdx.x;
    if (i >= NV4) return;
    float4 a = acc[i], n = hn[i];
    a.x += n.x; a.y += n.y; a.z += n.z; a.w += n.w;
    if (LAST) { a.x *= 0.25f; a.y *= 0.25f; a.z *= 0.25f; a.w *= 0.25f; }
    acc[i] = a;
    if (!LAST) zbuf[i] = make_float4(0.f, 0.f, 0.f, 0.f);
}

extern "C" void kernel_launch(void* const* d_in, const int* in_sizes, int n_in,
                              void* d_out, int out_size, void* d_ws, size_t ws_size,
                              hipStream_t stream) {
    const float* ue  = (const float*)d_in[0];
    const float* ie  = (const float*)d_in[1];
    const float* w   = (const float*)d_in[2];
    const int*   src = (const int*)d_in[3];
    const int*   dst = (const int*)d_in[4];

    float* out = (float*)d_out;

    // workspace layout (B=h1, C=h2, then CSR arrays, then packed edges)
    float* B    = (float*)d_ws;
    float* C    = B + NV;
    int*   offs = (int*)(C + NV);             // N_NODES+1
    int*   cur  = offs + (N_NODES + 1);       // N_NODES
    int*   csum = cur + N_NODES;              // 256 (+1 pad -> 8B align for pe)
    int2*  pe   = (int2*)(csum + 256 + 1);    // N_EDGES

    const size_t needed = (size_t)2 * NV * 4
                        + (size_t)(N_NODES + 1 + N_NODES + 256 + 1) * 4
                        + (size_t)N_EDGES * 8;

    const int TB = 256;
    const int egrid = NV4 / TB;                       // 31250
    const int ngrid = (N_EDGES + TB - 1) / TB;        // 4883
    const int fgrid = (N_NODES * 64) / TB;            // 125000

    if (ws_size >= needed) {
        // ---- CSR build ----
        hipMemsetAsync(cur, 0, (size_t)N_NODES * 4, stream);
        hist_kernel<<<ngrid, TB, 0, stream>>>(dst, cur);
        scan1_kernel<<<NCHUNK, 256, 0, stream>>>(cur, offs, csum);
        scan2_kernel<<<1, 256, 0, stream>>>(csum);
        scan3_kernel<<<(N_NODES + TB - 1) / TB, TB, 0, stream>>>(offs, csum);
        hipMemsetAsync(cur, 0, (size_t)N_NODES * 4, stream);
        scatter_kernel<<<ngrid, TB, 0, stream>>>(src, dst, w, offs, cur, pe);

        // ---- propagation ----
        layer_kernel<1><<<fgrid, TB, 0, stream>>>(nullptr, ue, ie, B, offs, pe); // h1
        layer_kernel<0><<<fgrid, TB, 0, stream>>>(B, ue, ie, C, offs, pe);       // h2
        final_kernel<<<fgrid, TB, 0, stream>>>(ue, ie, B, C, out, offs, pe);     // h3+mean
    } else {
        // ---- fallback: atomic path ----
        float* A  = (float*)d_ws;
        float* Bf = A + NV;
        const int sgrid = 4096;
        init_fb_kernel<<<egrid, TB, 0, stream>>>((const float4*)ue, (const float4*)ie,
                                                 (float4*)A, (float4*)Bf, (float4*)out);
        spmm_fb_kernel<<<sgrid, TB, 0, stream>>>(A, Bf, src, dst, w);
        accum_fb_kernel<0><<<egrid, TB, 0, stream>>>((float4*)out, (const float4*)Bf, (float4*)A);
        spmm_fb_kernel<<<sgrid, TB, 0, stream>>>(Bf, A, src, dst, w);
        accum_fb_kernel<0><<<egrid, TB, 0, stream>>>((float4*)out, (const float4*)A, (float4*)Bf);
        spmm_fb_kernel<<<sgrid, TB, 0, stream>>>(A, Bf, src, dst, w);
        accum_fb_kernel<1><<<egrid, TB, 0, stream>>>((float4*)out, (const float4*)Bf, nullptr);
    }
}

// Round 4
// 439.466 us; speedup vs baseline: 2.4560x; 1.5591x over previous
//
#include <hip/hip_runtime.h>

// LightGCN: out = 0.25*(h0 + h1 + h2 + h3), h_{k+1} = A_w · h_k.
// CSR-by-dst built on device; gather SpMM with float4 lanes:
// 16 lanes x float4 = one node's 64 dims, 4 independent dst nodes per wave
// -> up to 8 outstanding 256B gathers per wave (latency hiding).

#define USER_NUM  300000
#define ITEM_NUM  200000
#define N_NODES   500000
#define EMBED_DIM 64
#define N_EDGES   1250000
#define NV   (N_NODES * EMBED_DIM)   // 32,000,000 floats
#define NV4  (NV / 4)
#define CHUNK   2048
#define NCHUNK  ((N_NODES + CHUNK - 1) / CHUNK)   // 245

__device__ __forceinline__ float4 f4fma(float w, float4 g, float4 a) {
    a.x += w * g.x; a.y += w * g.y; a.z += w * g.z; a.w += w * g.w;
    return a;
}

// ---------------- CSR build ----------------
__global__ void hist_kernel(const int* __restrict__ dst, int* __restrict__ deg) {
    int e = blockIdx.x * blockDim.x + threadIdx.x;
    if (e < N_EDGES) atomicAdd(&deg[dst[e]], 1);
}

__global__ void scan1_kernel(const int* __restrict__ deg,
                             int* __restrict__ offs,
                             int* __restrict__ csum) {
    __shared__ int lds[256];
    int b = blockIdx.x, t = threadIdx.x;
    int base = b * CHUNK + t * 8;
    int v[8], sum = 0;
    #pragma unroll
    for (int i = 0; i < 8; ++i) {
        int idx = base + i;
        v[i] = (idx < N_NODES) ? deg[idx] : 0;
        sum += v[i];
    }
    lds[t] = sum;
    __syncthreads();
    for (int off = 1; off < 256; off <<= 1) {
        int x = (t >= off) ? lds[t - off] : 0;
        __syncthreads();
        if (t >= off) lds[t] += x;
        __syncthreads();
    }
    int excl = lds[t] - sum;
    if (t == 255) csum[b] = lds[255];
    int run = excl;
    #pragma unroll
    for (int i = 0; i < 8; ++i) {
        int idx = base + i;
        if (idx < N_NODES) offs[idx] = run;
        run += v[i];
    }
}

__global__ void scan2_kernel(int* __restrict__ csum) {
    __shared__ int lds[256];
    int t = threadIdx.x;
    int v = (t < NCHUNK) ? csum[t] : 0;
    lds[t] = v;
    __syncthreads();
    for (int off = 1; off < 256; off <<= 1) {
        int x = (t >= off) ? lds[t - off] : 0;
        __syncthreads();
        if (t >= off) lds[t] += x;
        __syncthreads();
    }
    if (t < NCHUNK) csum[t] = lds[t] - v;
}

__global__ void scan3_kernel(int* __restrict__ offs, const int* __restrict__ csum) {
    int i = blockIdx.x * blockDim.x + threadIdx.x;
    if (i < N_NODES) offs[i] += csum[i / CHUNK];
    if (i == 0) offs[N_NODES] = N_EDGES;
}

// pack sorted edge as int2{src, float_bits(w)}
__global__ void scatter_kernel(const int* __restrict__ src,
                               const int* __restrict__ dst,
                               const float* __restrict__ w,
                               const int* __restrict__ offs,
                               int* __restrict__ cur,
                               int2* __restrict__ pe) {
    int e = blockIdx.x * blockDim.x + threadIdx.x;
    if (e >= N_EDGES) return;
    int d = dst[e];
    int p = offs[d] + atomicAdd(&cur[d], 1);
    pe[p] = make_int2(src[e], __float_as_int(w[e]));
}

// ---------------- gather SpMM (float4 lanes, 4 nodes/wave) ----------------
__device__ __forceinline__ float4 gsrc4(const float4* __restrict__ hsrc,
                                        const float4* __restrict__ ue,
                                        const float4* __restrict__ ie,
                                        int s, int sub, bool fromEmb) {
    if (!fromEmb) return hsrc[(size_t)s * 16 + sub];
    // uniform within the 16-lane group (all share the same src node)
    return (s < USER_NUM) ? ue[(size_t)s * 16 + sub]
                          : ie[(size_t)(s - USER_NUM) * 16 + sub];
}

template <int FROM_EMB>
__global__ void layer_kernel(const float4* __restrict__ hsrc,
                             const float4* __restrict__ ue,
                             const float4* __restrict__ ie,
                             float4* __restrict__ hout,
                             const int* __restrict__ offs,
                             const int2* __restrict__ pe) {
    int gid  = blockIdx.x * blockDim.x + threadIdx.x;
    int wave = gid >> 6;
    int lane = gid & 63;
    int grp  = lane >> 4;          // 0..3 : which node this lane group owns
    int sub  = lane & 15;          // float4 slot within the node's 64 dims
    int n    = wave * 4 + grp;     // N_NODES % 4 == 0, no partial waves
    if (n >= N_NODES) return;
    int beg = offs[n], end = offs[n + 1];
    float4 s0 = make_float4(0.f, 0.f, 0.f, 0.f);
    float4 s1 = make_float4(0.f, 0.f, 0.f, 0.f);
    int e = beg;
    for (; e + 2 <= end; e += 2) {
        int2 p0 = pe[e], p1 = pe[e + 1];
        float4 g0 = gsrc4(hsrc, ue, ie, p0.x, sub, FROM_EMB);
        float4 g1 = gsrc4(hsrc, ue, ie, p1.x, sub, FROM_EMB);
        s0 = f4fma(__int_as_float(p0.y), g0, s0);
        s1 = f4fma(__int_as_float(p1.y), g1, s1);
    }
    if (e < end) {
        int2 p0 = pe[e];
        float4 g0 = gsrc4(hsrc, ue, ie, p0.x, sub, FROM_EMB);
        s0 = f4fma(__int_as_float(p0.y), g0, s0);
    }
    s0.x += s1.x; s0.y += s1.y; s0.z += s1.z; s0.w += s1.w;
    hout[(size_t)n * 16 + sub] = s0;
}

// gather h3 from h2, then out = 0.25*(h0 + h1 + h2 + h3); h0 from ue/ie
__global__ void final_kernel(const float4* __restrict__ ue,
                             const float4* __restrict__ ie,
                             const float4* __restrict__ h1,
                             const float4* __restrict__ h2,
                             float4* __restrict__ out,
                             const int* __restrict__ offs,
                             const int2* __restrict__ pe) {
    int gid  = blockIdx.x * blockDim.x + threadIdx.x;
    int wave = gid >> 6;
    int lane = gid & 63;
    int grp  = lane >> 4;
    int sub  = lane & 15;
    int n    = wave * 4 + grp;
    if (n >= N_NODES) return;
    int beg = offs[n], end = offs[n + 1];
    float4 s0 = make_float4(0.f, 0.f, 0.f, 0.f);
    float4 s1 = make_float4(0.f, 0.f, 0.f, 0.f);
    int e = beg;
    for (; e + 2 <= end; e += 2) {
        int2 p0 = pe[e], p1 = pe[e + 1];
        float4 g0 = h2[(size_t)p0.x * 16 + sub];
        float4 g1 = h2[(size_t)p1.x * 16 + sub];
        s0 = f4fma(__int_as_float(p0.y), g0, s0);
        s1 = f4fma(__int_as_float(p1.y), g1, s1);
    }
    if (e < end) {
        int2 p0 = pe[e];
        float4 g0 = h2[(size_t)p0.x * 16 + sub];
        s0 = f4fma(__int_as_float(p0.y), g0, s0);
    }
    size_t o = (size_t)n * 16 + sub;
    float4 a  = (n < USER_NUM) ? ue[o] : ie[o - (size_t)USER_NUM * 16];
    float4 b1 = h1[o], b2 = h2[o];
    float4 r;
    r.x = 0.25f * (a.x + b1.x + b2.x + s0.x + s1.x);
    r.y = 0.25f * (a.y + b1.y + b2.y + s0.y + s1.y);
    r.z = 0.25f * (a.z + b1.z + b2.z + s0.z + s1.z);
    r.w = 0.25f * (a.w + b1.w + b2.w + s0.w + s1.w);
    out[o] = r;
}

// ---------------- fallback (round-1 atomic) path ----------------
__global__ void init_fb_kernel(const float4* __restrict__ ue,
                               const float4* __restrict__ ie,
                               float4* __restrict__ h,
                               float4* __restrict__ hn,
                               float4* __restrict__ acc) {
    int i = blockIdx.x * blockDim.x + threadIdx.x;
    if (i >= NV4) return;
    const int ub = USER_NUM * EMBED_DIM / 4;
    float4 v = (i < ub) ? ue[i] : ie[i - ub];
    h[i] = v; acc[i] = v;
    hn[i] = make_float4(0.f, 0.f, 0.f, 0.f);
}

__global__ void spmm_fb_kernel(const float* __restrict__ h, float* __restrict__ hn,
                               const int* __restrict__ src, const int* __restrict__ dst,
                               const float* __restrict__ w) {
    int gid = blockIdx.x * blockDim.x + threadIdx.x;
    int wave = gid >> 6, lane = gid & 63;
    int nwave = (gridDim.x * blockDim.x) >> 6;
    for (int e = wave; e < N_EDGES; e += nwave) {
        float v = h[src[e] * 64 + lane] * w[e];
        atomicAdd(&hn[dst[e] * 64 + lane], v);
    }
}

template <int LAST>
__global__ void accum_fb_kernel(float4* __restrict__ acc, const float4* __restrict__ hn,
                                float4* __restrict__ zbuf) {
    int i = blockIdx.x * blockDim.x + threadIdx.x;
    if (i >= NV4) return;
    float4 a = acc[i], n = hn[i];
    a.x += n.x; a.y += n.y; a.z += n.z; a.w += n.w;
    if (LAST) { a.x *= 0.25f; a.y *= 0.25f; a.z *= 0.25f; a.w *= 0.25f; }
    acc[i] = a;
    if (!LAST) zbuf[i] = make_float4(0.f, 0.f, 0.f, 0.f);
}

extern "C" void kernel_launch(void* const* d_in, const int* in_sizes, int n_in,
                              void* d_out, int out_size, void* d_ws, size_t ws_size,
                              hipStream_t stream) {
    const float* ue  = (const float*)d_in[0];
    const float* ie  = (const float*)d_in[1];
    const float* w   = (const float*)d_in[2];
    const int*   src = (const int*)d_in[3];
    const int*   dst = (const int*)d_in[4];

    float* out = (float*)d_out;

    // workspace layout (B=h1, C=h2, CSR arrays, packed edges)
    float* B    = (float*)d_ws;
    float* C    = B + NV;
    int*   offs = (int*)(C + NV);             // N_NODES+1
    int*   cur  = offs + (N_NODES + 1);       // N_NODES
    int*   csum = cur + N_NODES;              // 256 (+1 pad -> 8B align)
    int2*  pe   = (int2*)(csum + 256 + 1);    // N_EDGES

    const size_t needed = (size_t)2 * NV * 4
                        + (size_t)(N_NODES + 1 + N_NODES + 256 + 1) * 4
                        + (size_t)N_EDGES * 8;

    const int TB = 256;
    const int egrid = NV4 / TB;                        // 31250
    const int ngrid = (N_EDGES + TB - 1) / TB;         // 4883
    const int fgrid = (N_NODES / 4 * 64) / TB;         // 31250 (4 nodes/wave)

    if (ws_size >= needed) {
        // ---- CSR build ----
        hipMemsetAsync(cur, 0, (size_t)N_NODES * 4, stream);
        hist_kernel<<<ngrid, TB, 0, stream>>>(dst, cur);
        scan1_kernel<<<NCHUNK, 256, 0, stream>>>(cur, offs, csum);
        scan2_kernel<<<1, 256, 0, stream>>>(csum);
        scan3_kernel<<<(N_NODES + TB - 1) / TB, TB, 0, stream>>>(offs, csum);
        hipMemsetAsync(cur, 0, (size_t)N_NODES * 4, stream);
        scatter_kernel<<<ngrid, TB, 0, stream>>>(src, dst, w, offs, cur, pe);

        // ---- propagation ----
        layer_kernel<1><<<fgrid, TB, 0, stream>>>(nullptr, (const float4*)ue,
                                                  (const float4*)ie, (float4*)B, offs, pe);
        layer_kernel<0><<<fgrid, TB, 0, stream>>>((const float4*)B, (const float4*)ue,
                                                  (const float4*)ie, (float4*)C, offs, pe);
        final_kernel<<<fgrid, TB, 0, stream>>>((const float4*)ue, (const float4*)ie,
                                               (const float4*)B, (const float4*)C,
                                               (float4*)out, offs, pe);
    } else {
        // ---- fallback: atomic path ----
        float* A  = (float*)d_ws;
        float* Bf = A + NV;
        const int sgrid = 4096;
        init_fb_kernel<<<egrid, TB, 0, stream>>>((const float4*)ue, (const float4*)ie,
                                                 (float4*)A, (float4*)Bf, (float4*)out);
        spmm_fb_kernel<<<sgrid, TB, 0, stream>>>(A, Bf, src, dst, w);
        accum_fb_kernel<0><<<egrid, TB, 0, stream>>>((float4*)out, (const float4*)Bf, (float4*)A);
        spmm_fb_kernel<<<sgrid, TB, 0, stream>>>(Bf, A, src, dst, w);
        accum_fb_kernel<0><<<egrid, TB, 0, stream>>>((float4*)out, (const float4*)A, (float4*)Bf);
        spmm_fb_kernel<<<sgrid, TB, 0, stream>>>(A, Bf, src, dst, w);
        accum_fb_kernel<1><<<egrid, TB, 0, stream>>>((float4*)out, (const float4*)Bf, nullptr);
    }
}

// Round 5
// 333.683 us; speedup vs baseline: 3.2346x; 1.3170x over previous
//
#include <hip/hip_runtime.h>

// LightGCN: out = 0.25*(h0 + h1 + h2 + h3), h_{k+1} = A_w · h_k.
// CSR-by-dst on device; gather SpMM. Intermediates h1,h2 stored bf16
// (f32 accumulate, RN pack): halves stream traffic, gather set fits L3.
// 8 lanes x uint4(8 bf16) = one node's 64 dims -> 8 dst nodes per wave.

#define USER_NUM  300000
#define ITEM_NUM  200000
#define N_NODES   500000
#define EMBED_DIM 64
#define N_EDGES   1250000
#define NV   (N_NODES * EMBED_DIM)   // 32,000,000 floats
#define NV4  (NV / 4)
#define CHUNK   2048
#define NCHUNK  ((N_NODES + CHUNK - 1) / CHUNK)   // 245

// ---------------- bf16 helpers (storage only; math in f32) ----------------
__device__ __forceinline__ unsigned bpack(float lo, float hi) {
    unsigned a = __float_as_uint(lo), b = __float_as_uint(hi);
    a = (a + 0x7fffu + ((a >> 16) & 1u)) >> 16;          // RN-to-even
    b = (b + 0x7fffu + ((b >> 16) & 1u)) & 0xffff0000u;
    return a | b;
}
__device__ __forceinline__ float blo(unsigned u) { return __uint_as_float(u << 16); }
__device__ __forceinline__ float bhi(unsigned u) { return __uint_as_float(u & 0xffff0000u); }

__device__ __forceinline__ void bf8_fma(uint4 g, float w, float* a) {
    a[0] += w * blo(g.x); a[1] += w * bhi(g.x);
    a[2] += w * blo(g.y); a[3] += w * bhi(g.y);
    a[4] += w * blo(g.z); a[5] += w * bhi(g.z);
    a[6] += w * blo(g.w); a[7] += w * bhi(g.w);
}

// ---------------- CSR build ----------------
__global__ void hist_kernel(const int* __restrict__ dst, int* __restrict__ deg) {
    int e = blockIdx.x * blockDim.x + threadIdx.x;
    if (e < N_EDGES) atomicAdd(&deg[dst[e]], 1);
}

__global__ void scan1_kernel(const int* __restrict__ deg,
                             int* __restrict__ offs,
                             int* __restrict__ csum) {
    __shared__ int lds[256];
    int b = blockIdx.x, t = threadIdx.x;
    int base = b * CHUNK + t * 8;
    int v[8], sum = 0;
    #pragma unroll
    for (int i = 0; i < 8; ++i) {
        int idx = base + i;
        v[i] = (idx < N_NODES) ? deg[idx] : 0;
        sum += v[i];
    }
    lds[t] = sum;
    __syncthreads();
    for (int off = 1; off < 256; off <<= 1) {
        int x = (t >= off) ? lds[t - off] : 0;
        __syncthreads();
        if (t >= off) lds[t] += x;
        __syncthreads();
    }
    int excl = lds[t] - sum;
    if (t == 255) csum[b] = lds[255];
    int run = excl;
    #pragma unroll
    for (int i = 0; i < 8; ++i) {
        int idx = base + i;
        if (idx < N_NODES) offs[idx] = run;
        run += v[i];
    }
}

__global__ void scan2_kernel(int* __restrict__ csum) {
    __shared__ int lds[256];
    int t = threadIdx.x;
    int v = (t < NCHUNK) ? csum[t] : 0;
    lds[t] = v;
    __syncthreads();
    for (int off = 1; off < 256; off <<= 1) {
        int x = (t >= off) ? lds[t - off] : 0;
        __syncthreads();
        if (t >= off) lds[t] += x;
        __syncthreads();
    }
    if (t < NCHUNK) csum[t] = lds[t] - v;
}

// final offsets -> offs; also copy into cur (scatter cursors, no 2nd memset)
__global__ void scan3_kernel(int* __restrict__ offs, const int* __restrict__ csum,
                             int* __restrict__ cur) {
    int i = blockIdx.x * blockDim.x + threadIdx.x;
    if (i < N_NODES) {
        int v = offs[i] + csum[i / CHUNK];
        offs[i] = v;
        cur[i]  = v;
    }
    if (i == 0) offs[N_NODES] = N_EDGES;
}

// pack sorted edge as int2{src, float_bits(w)}; cur pre-seeded with offs
__global__ void scatter_kernel(const int* __restrict__ src,
                               const int* __restrict__ dst,
                               const float* __restrict__ w,
                               int* __restrict__ cur,
                               int2* __restrict__ pe) {
    int e = blockIdx.x * blockDim.x + threadIdx.x;
    if (e >= N_EDGES) return;
    int p = atomicAdd(&cur[dst[e]], 1);
    pe[p] = make_int2(src[e], __float_as_int(w[e]));
}

// ---------------- propagation kernels (8 lanes/node, 8 nodes/wave) -------
// layer1: gather f32 emb -> write bf16 h1
__global__ void layer1_kernel(const float4* __restrict__ ue,
                              const float4* __restrict__ ie,
                              uint4* __restrict__ hout,
                              const int* __restrict__ offs,
                              const int2* __restrict__ pe) {
    int gid  = blockIdx.x * blockDim.x + threadIdx.x;
    int wave = gid >> 6;
    int lane = gid & 63;
    int grp  = lane >> 3;          // 0..7 node within wave
    int sub  = lane & 7;           // 8-dim slot (dims sub*8 .. sub*8+7)
    int n    = wave * 8 + grp;     // N_NODES % 8 == 0
    if (n >= N_NODES) return;
    int beg = offs[n], end = offs[n + 1];
    float a0[8] = {0,0,0,0,0,0,0,0};
    float a1[8] = {0,0,0,0,0,0,0,0};
    int e = beg;
    for (; e + 2 <= end; e += 2) {
        int2 p0 = pe[e], p1 = pe[e + 1];
        const float4* s0p = (p0.x < USER_NUM) ? &ue[(size_t)p0.x * 16]
                                              : &ie[(size_t)(p0.x - USER_NUM) * 16];
        const float4* s1p = (p1.x < USER_NUM) ? &ue[(size_t)p1.x * 16]
                                              : &ie[(size_t)(p1.x - USER_NUM) * 16];
        float4 g0a = s0p[sub * 2], g0b = s0p[sub * 2 + 1];
        float4 g1a = s1p[sub * 2], g1b = s1p[sub * 2 + 1];
        float w0 = __int_as_float(p0.y), w1 = __int_as_float(p1.y);
        a0[0] += w0 * g0a.x; a0[1] += w0 * g0a.y; a0[2] += w0 * g0a.z; a0[3] += w0 * g0a.w;
        a0[4] += w0 * g0b.x; a0[5] += w0 * g0b.y; a0[6] += w0 * g0b.z; a0[7] += w0 * g0b.w;
        a1[0] += w1 * g1a.x; a1[1] += w1 * g1a.y; a1[2] += w1 * g1a.z; a1[3] += w1 * g1a.w;
        a1[4] += w1 * g1b.x; a1[5] += w1 * g1b.y; a1[6] += w1 * g1b.z; a1[7] += w1 * g1b.w;
    }
    if (e < end) {
        int2 p0 = pe[e];
        const float4* s0p = (p0.x < USER_NUM) ? &ue[(size_t)p0.x * 16]
                                              : &ie[(size_t)(p0.x - USER_NUM) * 16];
        float4 g0a = s0p[sub * 2], g0b = s0p[sub * 2 + 1];
        float w0 = __int_as_float(p0.y);
        a0[0] += w0 * g0a.x; a0[1] += w0 * g0a.y; a0[2] += w0 * g0a.z; a0[3] += w0 * g0a.w;
        a0[4] += w0 * g0b.x; a0[5] += w0 * g0b.y; a0[6] += w0 * g0b.z; a0[7] += w0 * g0b.w;
    }
    #pragma unroll
    for (int i = 0; i < 8; ++i) a0[i] += a1[i];
    uint4 r;
    r.x = bpack(a0[0], a0[1]); r.y = bpack(a0[2], a0[3]);
    r.z = bpack(a0[4], a0[5]); r.w = bpack(a0[6], a0[7]);
    hout[(size_t)n * 8 + sub] = r;
}

// layer2: gather bf16 -> write bf16
__global__ void layer2_kernel(const uint4* __restrict__ hsrc,
                              uint4* __restrict__ hout,
                              const int* __restrict__ offs,
                              const int2* __restrict__ pe) {
    int gid  = blockIdx.x * blockDim.x + threadIdx.x;
    int wave = gid >> 6;
    int lane = gid & 63;
    int grp  = lane >> 3;
    int sub  = lane & 7;
    int n    = wave * 8 + grp;
    if (n >= N_NODES) return;
    int beg = offs[n], end = offs[n + 1];
    float a0[8] = {0,0,0,0,0,0,0,0};
    float a1[8] = {0,0,0,0,0,0,0,0};
    int e = beg;
    for (; e + 2 <= end; e += 2) {
        int2 p0 = pe[e], p1 = pe[e + 1];
        uint4 g0 = hsrc[(size_t)p0.x * 8 + sub];
        uint4 g1 = hsrc[(size_t)p1.x * 8 + sub];
        bf8_fma(g0, __int_as_float(p0.y), a0);
        bf8_fma(g1, __int_as_float(p1.y), a1);
    }
    if (e < end) {
        int2 p0 = pe[e];
        uint4 g0 = hsrc[(size_t)p0.x * 8 + sub];
        bf8_fma(g0, __int_as_float(p0.y), a0);
    }
    #pragma unroll
    for (int i = 0; i < 8; ++i) a0[i] += a1[i];
    uint4 r;
    r.x = bpack(a0[0], a0[1]); r.y = bpack(a0[2], a0[3]);
    r.z = bpack(a0[4], a0[5]); r.w = bpack(a0[6], a0[7]);
    hout[(size_t)n * 8 + sub] = r;
}

// final: gather h3 from bf16 h2; out = 0.25*(h0(f32 emb) + h1 + h2 + h3)
__global__ void final_kernel(const float4* __restrict__ ue,
                             const float4* __restrict__ ie,
                             const uint4* __restrict__ h1,
                             const uint4* __restrict__ h2,
                             float4* __restrict__ out,
                             const int* __restrict__ offs,
                             const int2* __restrict__ pe) {
    int gid  = blockIdx.x * blockDim.x + threadIdx.x;
    int wave = gid >> 6;
    int lane = gid & 63;
    int grp  = lane >> 3;
    int sub  = lane & 7;
    int n    = wave * 8 + grp;
    if (n >= N_NODES) return;
    int beg = offs[n], end = offs[n + 1];
    float a0[8] = {0,0,0,0,0,0,0,0};
    float a1[8] = {0,0,0,0,0,0,0,0};
    int e = beg;
    for (; e + 2 <= end; e += 2) {
        int2 p0 = pe[e], p1 = pe[e + 1];
        uint4 g0 = h2[(size_t)p0.x * 8 + sub];
        uint4 g1 = h2[(size_t)p1.x * 8 + sub];
        bf8_fma(g0, __int_as_float(p0.y), a0);
        bf8_fma(g1, __int_as_float(p1.y), a1);
    }
    if (e < end) {
        int2 p0 = pe[e];
        uint4 g0 = h2[(size_t)p0.x * 8 + sub];
        bf8_fma(g0, __int_as_float(p0.y), a0);
    }
    size_t o8 = (size_t)n * 8 + sub;
    uint4 b1 = h1[o8], b2 = h2[o8];
    const float4* e0p = (n < USER_NUM) ? &ue[(size_t)n * 16]
                                       : &ie[(size_t)(n - USER_NUM) * 16];
    float4 e0a = e0p[sub * 2], e0b = e0p[sub * 2 + 1];
    float4 ra, rb;
    ra.x = 0.25f * (e0a.x + blo(b1.x) + blo(b2.x) + a0[0] + a1[0]);
    ra.y = 0.25f * (e0a.y + bhi(b1.x) + bhi(b2.x) + a0[1] + a1[1]);
    ra.z = 0.25f * (e0a.z + blo(b1.y) + blo(b2.y) + a0[2] + a1[2]);
    ra.w = 0.25f * (e0a.w + bhi(b1.y) + bhi(b2.y) + a0[3] + a1[3]);
    rb.x = 0.25f * (e0b.x + blo(b1.z) + blo(b2.z) + a0[4] + a1[4]);
    rb.y = 0.25f * (e0b.y + bhi(b1.z) + bhi(b2.z) + a0[5] + a1[5]);
    rb.z = 0.25f * (e0b.z + blo(b1.w) + blo(b2.w) + a0[6] + a1[6]);
    rb.w = 0.25f * (e0b.w + bhi(b1.w) + bhi(b2.w) + a0[7] + a1[7]);
    out[(size_t)n * 16 + sub * 2]     = ra;
    out[(size_t)n * 16 + sub * 2 + 1] = rb;
}

// ---------------- fallback (round-1 atomic) path ----------------
__global__ void init_fb_kernel(const float4* __restrict__ ue,
                               const float4* __restrict__ ie,
                               float4* __restrict__ h,
                               float4* __restrict__ hn,
                               float4* __restrict__ acc) {
    int i = blockIdx.x * blockDim.x + threadIdx.x;
    if (i >= NV4) return;
    const int ub = USER_NUM * EMBED_DIM / 4;
    float4 v = (i < ub) ? ue[i] : ie[i - ub];
    h[i] = v; acc[i] = v;
    hn[i] = make_float4(0.f, 0.f, 0.f, 0.f);
}

__global__ void spmm_fb_kernel(const float* __restrict__ h, float* __restrict__ hn,
                               const int* __restrict__ src, const int* __restrict__ dst,
                               const float* __restrict__ w) {
    int gid = blockIdx.x * blockDim.x + threadIdx.x;
    int wave = gid >> 6, lane = gid & 63;
    int nwave = (gridDim.x * blockDim.x) >> 6;
    for (int e = wave; e < N_EDGES; e += nwave) {
        float v = h[src[e] * 64 + lane] * w[e];
        atomicAdd(&hn[dst[e] * 64 + lane], v);
    }
}

template <int LAST>
__global__ void accum_fb_kernel(float4* __restrict__ acc, const float4* __restrict__ hn,
                                float4* __restrict__ zbuf) {
    int i = blockIdx.x * blockDim.x + threadIdx.x;
    if (i >= NV4) return;
    float4 a = acc[i], n = hn[i];
    a.x += n.x; a.y += n.y; a.z += n.z; a.w += n.w;
    if (LAST) { a.x *= 0.25f; a.y *= 0.25f; a.z *= 0.25f; a.w *= 0.25f; }
    acc[i] = a;
    if (!LAST) zbuf[i] = make_float4(0.f, 0.f, 0.f, 0.f);
}

extern "C" void kernel_launch(void* const* d_in, const int* in_sizes, int n_in,
                              void* d_out, int out_size, void* d_ws, size_t ws_size,
                              hipStream_t stream) {
    const float* ue  = (const float*)d_in[0];
    const float* ie  = (const float*)d_in[1];
    const float* w   = (const float*)d_in[2];
    const int*   src = (const int*)d_in[3];
    const int*   dst = (const int*)d_in[4];

    float* out = (float*)d_out;

    // workspace layout: B=h1(bf16), C=h2(bf16), CSR arrays, packed edges
    const size_t HB = (size_t)N_NODES * 128;   // bf16 h buffer bytes (64 MB)
    char*  base = (char*)d_ws;
    uint4* B    = (uint4*)base;
    uint4* C    = (uint4*)(base + HB);
    int*   offs = (int*)(base + 2 * HB);      // N_NODES+1
    int*   cur  = offs + (N_NODES + 1);       // N_NODES
    int*   csum = cur + N_NODES;              // 256 (+1 pad -> 8B align)
    int2*  pe   = (int2*)(csum + 256 + 1);    // N_EDGES

    const size_t needed = 2 * HB
                        + (size_t)(N_NODES + 1 + N_NODES + 256 + 1) * 4
                        + (size_t)N_EDGES * 8;

    const int TB = 256;
    const int egrid = NV4 / TB;                        // 31250
    const int ngrid = (N_EDGES + TB - 1) / TB;         // 4883
    const int fgrid = (N_NODES / 8 * 64) / TB;         // 15625 (8 nodes/wave)

    if (ws_size >= needed) {
        // ---- CSR build ----
        hipMemsetAsync(cur, 0, (size_t)N_NODES * 4, stream);
        hist_kernel<<<ngrid, TB, 0, stream>>>(dst, cur);
        scan1_kernel<<<NCHUNK, 256, 0, stream>>>(cur, offs, csum);
        scan2_kernel<<<1, 256, 0, stream>>>(csum);
        scan3_kernel<<<(N_NODES + TB - 1) / TB, TB, 0, stream>>>(offs, csum, cur);
        scatter_kernel<<<ngrid, TB, 0, stream>>>(src, dst, w, cur, pe);

        // ---- propagation ----
        layer1_kernel<<<fgrid, TB, 0, stream>>>((const float4*)ue, (const float4*)ie,
                                                B, offs, pe);
        layer2_kernel<<<fgrid, TB, 0, stream>>>(B, C, offs, pe);
        final_kernel<<<fgrid, TB, 0, stream>>>((const float4*)ue, (const float4*)ie,
                                               B, C, (float4*)out, offs, pe);
    } else {
        // ---- fallback: atomic path (f32, needs 256 MB ws) ----
        float* A  = (float*)d_ws;
        float* Bf = A + NV;
        const int sgrid = 4096;
        init_fb_kernel<<<egrid, TB, 0, stream>>>((const float4*)ue, (const float4*)ie,
                                                 (float4*)A, (float4*)Bf, (float4*)out);
        spmm_fb_kernel<<<sgrid, TB, 0, stream>>>(A, Bf, src, dst, w);
        accum_fb_kernel<0><<<egrid, TB, 0, stream>>>((float4*)out, (const float4*)Bf, (float4*)A);
        spmm_fb_kernel<<<sgrid, TB, 0, stream>>>(Bf, A, src, dst, w);
        accum_fb_kernel<0><<<egrid, TB, 0, stream>>>((float4*)out, (const float4*)A, (float4*)Bf);
        spmm_fb_kernel<<<sgrid, TB, 0, stream>>>(A, Bf, src, dst, w);
        accum_fb_kernel<1><<<egrid, TB, 0, stream>>>((float4*)out, (const float4*)Bf, nullptr);
    }
}

// Round 6
// 252.192 us; speedup vs baseline: 4.2797x; 1.3231x over previous
//
#include <hip/hip_runtime.h>

// LightGCN: out = 0.25*(h0 + h1 + h2 + h3), h_{k+1} = A_w · h_k.
// CSR-by-dst built per call via two-level partition (coarse 245 buckets ->
// per-bucket fine sort with LDS cursors) to keep scatter writes L2-local.
// Intermediates h1,h2 stored bf16 (f32 accumulate). Gather SpMM, 8 nodes/wave.

#define USER_NUM  300000
#define ITEM_NUM  200000
#define N_NODES   500000
#define EMBED_DIM 64
#define N_EDGES   1250000
#define NV   (N_NODES * EMBED_DIM)   // 32,000,000 floats
#define NV4  (NV / 4)

#define BSHIFT  11
#define BNODES  2048                               // nodes per coarse bucket
#define NBUK    ((N_NODES + BNODES - 1) / BNODES)  // 245
#define PCHUNK  4096                               // edges per partition block
#define PGRID   ((N_EDGES + PCHUNK - 1) / PCHUNK)  // 306

// ---------------- bf16 helpers (storage only; math in f32) ----------------
__device__ __forceinline__ unsigned bpack(float lo, float hi) {
    unsigned a = __float_as_uint(lo), b = __float_as_uint(hi);
    a = (a + 0x7fffu + ((a >> 16) & 1u)) >> 16;          // RN-to-even
    b = (b + 0x7fffu + ((b >> 16) & 1u)) & 0xffff0000u;
    return a | b;
}
__device__ __forceinline__ float blo(unsigned u) { return __uint_as_float(u << 16); }
__device__ __forceinline__ float bhi(unsigned u) { return __uint_as_float(u & 0xffff0000u); }

__device__ __forceinline__ void bf8_fma(uint4 g, float w, float* a) {
    a[0] += w * blo(g.x); a[1] += w * bhi(g.x);
    a[2] += w * blo(g.y); a[3] += w * bhi(g.y);
    a[4] += w * blo(g.z); a[5] += w * bhi(g.z);
    a[6] += w * blo(g.w); a[7] += w * bhi(g.w);
}

// ---------------- CSR build: two-level partition ----------------
// 1) coarse bucket histogram (LDS-staged -> few global atomics)
__global__ void bhist_kernel(const int* __restrict__ dst, int* __restrict__ bcnt) {
    __shared__ int h[256];
    int t = threadIdx.x;
    h[t] = 0;
    __syncthreads();
    int cbase = blockIdx.x * PCHUNK;
    int cnt = min(PCHUNK, N_EDGES - cbase);
    for (int i = t; i < cnt; i += 256)
        atomicAdd(&h[dst[cbase + i] >> BSHIFT], 1);
    __syncthreads();
    if (t < NBUK && h[t]) atomicAdd(&bcnt[t], h[t]);
}

// 2) scan bucket counts -> boff[NBUK+1], bcur (reservation cursors)
__global__ void bscan_kernel(const int* __restrict__ bcnt,
                             int* __restrict__ boff,
                             int* __restrict__ bcur,
                             int* __restrict__ offs) {
    __shared__ int lds[256];
    int t = threadIdx.x;
    int v = (t < NBUK) ? bcnt[t] : 0;
    lds[t] = v;
    __syncthreads();
    for (int off = 1; off < 256; off <<= 1) {
        int x = (t >= off) ? lds[t - off] : 0;
        __syncthreads();
        if (t >= off) lds[t] += x;
        __syncthreads();
    }
    int excl = lds[t] - v;
    if (t < NBUK) { boff[t] = excl; bcur[t] = excl; }
    if (t == NBUK - 1) boff[NBUK] = N_EDGES;
    if (t == 0) offs[N_NODES] = N_EDGES;
}

// 3) partition edges into coarse buckets: per-chunk LDS hist + one global
//    reservation per (bucket, chunk) -> writes are short contiguous runs.
__global__ void part_kernel(const int* __restrict__ src,
                            const int* __restrict__ dst,
                            const float* __restrict__ w,
                            int* __restrict__ bcur,
                            int4* __restrict__ tmp) {
    __shared__ int hist[256];
    __shared__ int base[256];
    int t = threadIdx.x;
    int cbase = blockIdx.x * PCHUNK;
    int cnt = min(PCHUNK, N_EDGES - cbase);
    int es[16], ed[16];
    float ew[16];
    hist[t] = 0;
    __syncthreads();
    #pragma unroll
    for (int k = 0; k < 16; ++k) {
        int i = t + k * 256;
        if (i < cnt) {
            int e = cbase + i;
            es[k] = src[e]; ed[k] = dst[e]; ew[k] = w[e];
            atomicAdd(&hist[ed[k] >> BSHIFT], 1);
        } else ed[k] = -1;
    }
    __syncthreads();
    int h = hist[t];
    base[t] = (h > 0) ? atomicAdd(&bcur[t], h) : 0;
    __syncthreads();
    hist[t] = 0;                     // reuse as local cursor
    __syncthreads();
    #pragma unroll
    for (int k = 0; k < 16; ++k) {
        if (ed[k] >= 0) {
            int b = ed[k] >> BSHIFT;
            int r = atomicAdd(&hist[b], 1);
            tmp[base[b] + r] = make_int4(es[k], __float_as_int(ew[k]), ed[k], 0);
        }
    }
}

// 4) per-bucket fine sort: LDS per-node counts + scan -> writes offs AND
//    scatters pe into the bucket's contiguous (L2-local) region.
__global__ void fine_kernel(const int4* __restrict__ tmp,
                            const int* __restrict__ boff,
                            int* __restrict__ offs,
                            int2* __restrict__ pe) {
    __shared__ int cnt[BNODES];
    __shared__ int sums[256];
    int b = blockIdx.x, t = threadIdx.x;
    int nbase = b << BSHIFT;
    int ebeg = boff[b], eend = boff[b + 1];
    for (int j = t; j < BNODES; j += 256) cnt[j] = 0;
    __syncthreads();
    for (int i = ebeg + t; i < eend; i += 256)
        atomicAdd(&cnt[tmp[i].z - nbase], 1);
    __syncthreads();
    int s[8], tot = 0;
    #pragma unroll
    for (int k = 0; k < 8; ++k) { s[k] = cnt[t * 8 + k]; tot += s[k]; }
    sums[t] = tot;
    __syncthreads();
    for (int off = 1; off < 256; off <<= 1) {
        int x = (t >= off) ? sums[t - off] : 0;
        __syncthreads();
        if (t >= off) sums[t] += x;
        __syncthreads();
    }
    int run = ebeg + sums[t] - tot;
    #pragma unroll
    for (int k = 0; k < 8; ++k) {
        int node = nbase + t * 8 + k;
        if (node < N_NODES) offs[node] = run;
        cnt[t * 8 + k] = run;        // cursor
        run += s[k];
    }
    __syncthreads();
    for (int i = ebeg + t; i < eend; i += 256) {
        int4 E = tmp[i];
        int p = atomicAdd(&cnt[E.z - nbase], 1);
        pe[p] = make_int2(E.x, E.y);
    }
}

// ---------------- propagation kernels (8 lanes/node, 8 nodes/wave) -------
__global__ void layer1_kernel(const float4* __restrict__ ue,
                              const float4* __restrict__ ie,
                              uint4* __restrict__ hout,
                              const int* __restrict__ offs,
                              const int2* __restrict__ pe) {
    int gid  = blockIdx.x * blockDim.x + threadIdx.x;
    int wave = gid >> 6;
    int lane = gid & 63;
    int grp  = lane >> 3;
    int sub  = lane & 7;
    int n    = wave * 8 + grp;
    if (n >= N_NODES) return;
    int beg = offs[n], end = offs[n + 1];
    float a0[8] = {0,0,0,0,0,0,0,0};
    float a1[8] = {0,0,0,0,0,0,0,0};
    int e = beg;
    for (; e + 2 <= end; e += 2) {
        int2 p0 = pe[e], p1 = pe[e + 1];
        const float4* s0p = (p0.x < USER_NUM) ? &ue[(size_t)p0.x * 16]
                                              : &ie[(size_t)(p0.x - USER_NUM) * 16];
        const float4* s1p = (p1.x < USER_NUM) ? &ue[(size_t)p1.x * 16]
                                              : &ie[(size_t)(p1.x - USER_NUM) * 16];
        float4 g0a = s0p[sub * 2], g0b = s0p[sub * 2 + 1];
        float4 g1a = s1p[sub * 2], g1b = s1p[sub * 2 + 1];
        float w0 = __int_as_float(p0.y), w1 = __int_as_float(p1.y);
        a0[0] += w0 * g0a.x; a0[1] += w0 * g0a.y; a0[2] += w0 * g0a.z; a0[3] += w0 * g0a.w;
        a0[4] += w0 * g0b.x; a0[5] += w0 * g0b.y; a0[6] += w0 * g0b.z; a0[7] += w0 * g0b.w;
        a1[0] += w1 * g1a.x; a1[1] += w1 * g1a.y; a1[2] += w1 * g1a.z; a1[3] += w1 * g1a.w;
        a1[4] += w1 * g1b.x; a1[5] += w1 * g1b.y; a1[6] += w1 * g1b.z; a1[7] += w1 * g1b.w;
    }
    if (e < end) {
        int2 p0 = pe[e];
        const float4* s0p = (p0.x < USER_NUM) ? &ue[(size_t)p0.x * 16]
                                              : &ie[(size_t)(p0.x - USER_NUM) * 16];
        float4 g0a = s0p[sub * 2], g0b = s0p[sub * 2 + 1];
        float w0 = __int_as_float(p0.y);
        a0[0] += w0 * g0a.x; a0[1] += w0 * g0a.y; a0[2] += w0 * g0a.z; a0[3] += w0 * g0a.w;
        a0[4] += w0 * g0b.x; a0[5] += w0 * g0b.y; a0[6] += w0 * g0b.z; a0[7] += w0 * g0b.w;
    }
    #pragma unroll
    for (int i = 0; i < 8; ++i) a0[i] += a1[i];
    uint4 r;
    r.x = bpack(a0[0], a0[1]); r.y = bpack(a0[2], a0[3]);
    r.z = bpack(a0[4], a0[5]); r.w = bpack(a0[6], a0[7]);
    hout[(size_t)n * 8 + sub] = r;
}

__global__ void layer2_kernel(const uint4* __restrict__ hsrc,
                              uint4* __restrict__ hout,
                              const int* __restrict__ offs,
                              const int2* __restrict__ pe) {
    int gid  = blockIdx.x * blockDim.x + threadIdx.x;
    int wave = gid >> 6;
    int lane = gid & 63;
    int grp  = lane >> 3;
    int sub  = lane & 7;
    int n    = wave * 8 + grp;
    if (n >= N_NODES) return;
    int beg = offs[n], end = offs[n + 1];
    float a0[8] = {0,0,0,0,0,0,0,0};
    float a1[8] = {0,0,0,0,0,0,0,0};
    int e = beg;
    for (; e + 2 <= end; e += 2) {
        int2 p0 = pe[e], p1 = pe[e + 1];
        uint4 g0 = hsrc[(size_t)p0.x * 8 + sub];
        uint4 g1 = hsrc[(size_t)p1.x * 8 + sub];
        bf8_fma(g0, __int_as_float(p0.y), a0);
        bf8_fma(g1, __int_as_float(p1.y), a1);
    }
    if (e < end) {
        int2 p0 = pe[e];
        uint4 g0 = hsrc[(size_t)p0.x * 8 + sub];
        bf8_fma(g0, __int_as_float(p0.y), a0);
    }
    #pragma unroll
    for (int i = 0; i < 8; ++i) a0[i] += a1[i];
    uint4 r;
    r.x = bpack(a0[0], a0[1]); r.y = bpack(a0[2], a0[3]);
    r.z = bpack(a0[4], a0[5]); r.w = bpack(a0[6], a0[7]);
    hout[(size_t)n * 8 + sub] = r;
}

__global__ void final_kernel(const float4* __restrict__ ue,
                             const float4* __restrict__ ie,
                             const uint4* __restrict__ h1,
                             const uint4* __restrict__ h2,
                             float4* __restrict__ out,
                             const int* __restrict__ offs,
                             const int2* __restrict__ pe) {
    int gid  = blockIdx.x * blockDim.x + threadIdx.x;
    int wave = gid >> 6;
    int lane = gid & 63;
    int grp  = lane >> 3;
    int sub  = lane & 7;
    int n    = wave * 8 + grp;
    if (n >= N_NODES) return;
    int beg = offs[n], end = offs[n + 1];
    float a0[8] = {0,0,0,0,0,0,0,0};
    float a1[8] = {0,0,0,0,0,0,0,0};
    int e = beg;
    for (; e + 2 <= end; e += 2) {
        int2 p0 = pe[e], p1 = pe[e + 1];
        uint4 g0 = h2[(size_t)p0.x * 8 + sub];
        uint4 g1 = h2[(size_t)p1.x * 8 + sub];
        bf8_fma(g0, __int_as_float(p0.y), a0);
        bf8_fma(g1, __int_as_float(p1.y), a1);
    }
    if (e < end) {
        int2 p0 = pe[e];
        uint4 g0 = h2[(size_t)p0.x * 8 + sub];
        bf8_fma(g0, __int_as_float(p0.y), a0);
    }
    size_t o8 = (size_t)n * 8 + sub;
    uint4 b1 = h1[o8], b2 = h2[o8];
    const float4* e0p = (n < USER_NUM) ? &ue[(size_t)n * 16]
                                       : &ie[(size_t)(n - USER_NUM) * 16];
    float4 e0a = e0p[sub * 2], e0b = e0p[sub * 2 + 1];
    float4 ra, rb;
    ra.x = 0.25f * (e0a.x + blo(b1.x) + blo(b2.x) + a0[0] + a1[0]);
    ra.y = 0.25f * (e0a.y + bhi(b1.x) + bhi(b2.x) + a0[1] + a1[1]);
    ra.z = 0.25f * (e0a.z + blo(b1.y) + blo(b2.y) + a0[2] + a1[2]);
    ra.w = 0.25f * (e0a.w + bhi(b1.y) + bhi(b2.y) + a0[3] + a1[3]);
    rb.x = 0.25f * (e0b.x + blo(b1.z) + blo(b2.z) + a0[4] + a1[4]);
    rb.y = 0.25f * (e0b.y + bhi(b1.z) + bhi(b2.z) + a0[5] + a1[5]);
    rb.z = 0.25f * (e0b.z + blo(b1.w) + blo(b2.w) + a0[6] + a1[6]);
    rb.w = 0.25f * (e0b.w + bhi(b1.w) + bhi(b2.w) + a0[7] + a1[7]);
    out[(size_t)n * 16 + sub * 2]     = ra;
    out[(size_t)n * 16 + sub * 2 + 1] = rb;
}

// ---------------- fallback (round-1 atomic) path ----------------
__global__ void init_fb_kernel(const float4* __restrict__ ue,
                               const float4* __restrict__ ie,
                               float4* __restrict__ h,
                               float4* __restrict__ hn,
                               float4* __restrict__ acc) {
    int i = blockIdx.x * blockDim.x + threadIdx.x;
    if (i >= NV4) return;
    const int ub = USER_NUM * EMBED_DIM / 4;
    float4 v = (i < ub) ? ue[i] : ie[i - ub];
    h[i] = v; acc[i] = v;
    hn[i] = make_float4(0.f, 0.f, 0.f, 0.f);
}

__global__ void spmm_fb_kernel(const float* __restrict__ h, float* __restrict__ hn,
                               const int* __restrict__ src, const int* __restrict__ dst,
                               const float* __restrict__ w) {
    int gid = blockIdx.x * blockDim.x + threadIdx.x;
    int wave = gid >> 6, lane = gid & 63;
    int nwave = (gridDim.x * blockDim.x) >> 6;
    for (int e = wave; e < N_EDGES; e += nwave) {
        float v = h[src[e] * 64 + lane] * w[e];
        atomicAdd(&hn[dst[e] * 64 + lane], v);
    }
}

template <int LAST>
__global__ void accum_fb_kernel(float4* __restrict__ acc, const float4* __restrict__ hn,
                                float4* __restrict__ zbuf) {
    int i = blockIdx.x * blockDim.x + threadIdx.x;
    if (i >= NV4) return;
    float4 a = acc[i], n = hn[i];
    a.x += n.x; a.y += n.y; a.z += n.z; a.w += n.w;
    if (LAST) { a.x *= 0.25f; a.y *= 0.25f; a.z *= 0.25f; a.w *= 0.25f; }
    acc[i] = a;
    if (!LAST) zbuf[i] = make_float4(0.f, 0.f, 0.f, 0.f);
}

extern "C" void kernel_launch(void* const* d_in, const int* in_sizes, int n_in,
                              void* d_out, int out_size, void* d_ws, size_t ws_size,
                              hipStream_t stream) {
    const float* ue  = (const float*)d_in[0];
    const float* ie  = (const float*)d_in[1];
    const float* w   = (const float*)d_in[2];
    const int*   src = (const int*)d_in[3];
    const int*   dst = (const int*)d_in[4];

    float* out = (float*)d_out;

    // workspace: B=h1(bf16,64MB), C=h2(bf16,64MB), tmp(int4,20MB),
    //            pe(int2,10MB), offs, boff, bcnt, bcur
    const size_t HB = (size_t)N_NODES * 128;
    char*  base = (char*)d_ws;
    uint4* B    = (uint4*)base;
    uint4* C    = (uint4*)(base + HB);
    int4*  tmp  = (int4*)(base + 2 * HB);                 // N_EDGES
    int2*  pe   = (int2*)(base + 2 * HB + (size_t)N_EDGES * 16);
    int*   offs = (int*)((char*)pe + (size_t)N_EDGES * 8); // N_NODES+1
    int*   boff = offs + (N_NODES + 1);                    // NBUK+1
    int*   bcnt = boff + (NBUK + 1);                       // NBUK
    int*   bcur = bcnt + NBUK;                             // NBUK

    const size_t needed = 2 * HB + (size_t)N_EDGES * 24
                        + (size_t)(N_NODES + 1 + 3 * NBUK + 1) * 4;

    const int TB = 256;
    const int egrid = NV4 / TB;
    const int fgrid = (N_NODES / 8 * 64) / TB;    // 15625 (8 nodes/wave)

    if (ws_size >= needed) {
        // ---- CSR build (two-level partition) ----
        hipMemsetAsync(bcnt, 0, (size_t)NBUK * 4, stream);
        bhist_kernel<<<PGRID, TB, 0, stream>>>(dst, bcnt);
        bscan_kernel<<<1, 256, 0, stream>>>(bcnt, boff, bcur, offs);
        part_kernel<<<PGRID, TB, 0, stream>>>(src, dst, w, bcur, tmp);
        fine_kernel<<<NBUK, TB, 0, stream>>>(tmp, boff, offs, pe);

        // ---- propagation ----
        layer1_kernel<<<fgrid, TB, 0, stream>>>((const float4*)ue, (const float4*)ie,
                                                B, offs, pe);
        layer2_kernel<<<fgrid, TB, 0, stream>>>(B, C, offs, pe);
        final_kernel<<<fgrid, TB, 0, stream>>>((const float4*)ue, (const float4*)ie,
                                               B, C, (float4*)out, offs, pe);
    } else {
        // ---- fallback: atomic path ----
        float* A  = (float*)d_ws;
        float* Bf = A + NV;
        const int sgrid = 4096;
        init_fb_kernel<<<egrid, TB, 0, stream>>>((const float4*)ue, (const float4*)ie,
                                                 (float4*)A, (float4*)Bf, (float4*)out);
        spmm_fb_kernel<<<sgrid, TB, 0, stream>>>(A, Bf, src, dst, w);
        accum_fb_kernel<0><<<egrid, TB, 0, stream>>>((float4*)out, (const float4*)Bf, (float4*)A);
        spmm_fb_kernel<<<sgrid, TB, 0, stream>>>(Bf, A, src, dst, w);
        accum_fb_kernel<0><<<egrid, TB, 0, stream>>>((float4*)out, (const float4*)A, (float4*)Bf);
        spmm_fb_kernel<<<sgrid, TB, 0, stream>>>(A, Bf, src, dst, w);
        accum_fb_kernel<1><<<egrid, TB, 0, stream>>>((float4*)out, (const float4*)Bf, nullptr);
    }
}